// Round 2
// baseline (764.389 us; speedup 1.0000x reference)
//
#include <hip/hip_runtime.h>
#include <hip/hip_bf16.h>
#include <cstdint>
#include <cstddef>

#define DIN 256
#define DOUT 128

typedef __bf16 bf16x8 __attribute__((ext_vector_type(8)));
typedef float f32x4 __attribute__((ext_vector_type(4)));

union U16x8 { uint4 u; bf16x8 v; unsigned short s[8]; };

__device__ __forceinline__ float bf2f(unsigned short s) {
    union { unsigned int u; float f; } c; c.u = ((unsigned int)s) << 16; return c.f;
}
__device__ __forceinline__ unsigned short f2bf(float f) {
    union { float f; unsigned int u; } c; c.f = f;
    unsigned int u = c.u;
    unsigned int r = (u + 0x7fffu + ((u >> 16) & 1u)) >> 16;
    return (unsigned short)r;
}

// ---------------- dtype detect: values are exactly +-1.0 --------------------
// fp32 +-1.0 word = 0x3F800000/0xBF800000 (low16 == 0); bf16 pair word has
// 0x3F80/0xBF80 in the low half (nonzero). flag=1 -> float32 inputs.
__global__ void k_detect(const unsigned int* __restrict__ vals, int* __restrict__ flag) {
    if (threadIdx.x == 0 && blockIdx.x == 0)
        flag[0] = ((vals[0] & 0xFFFFu) == 0u) ? 1 : 0;
}

// ---------------- prep: zero counts + build swizzled W (B-fragment order) ---
__global__ __launch_bounds__(256) void k_prep(const void* __restrict__ W,
                                              unsigned short* __restrict__ Wsw,
                                              int* __restrict__ counts,
                                              const int* __restrict__ flag, int N) {
    int g = blockIdx.x * 256 + threadIdx.x;
    if (g < N) counts[g] = 0;
    if (g < 8 * 8 * 64) {
        int is_f32 = flag[0];
        int lane = g & 63;
        int st = g >> 6;            // s*8 + t
        int s = st >> 3, t = st & 7;
        int quad = lane >> 4, c = lane & 15;
        int kbase = s * 32 + quad * 8;
        int col = t * 16 + c;
        U16x8 u;
#pragma unroll
        for (int j = 0; j < 8; ++j) {
            size_t idx = (size_t)(kbase + j) * DOUT + col;
            u.s[j] = is_f32 ? f2bf(((const float*)W)[idx])
                            : ((const unsigned short*)W)[idx];
        }
        ((uint4*)Wsw)[g] = u.u;
    }
}

// ---------------- histogram -------------------------------------------------
__global__ __launch_bounds__(256) void k_hist(const int* __restrict__ row,
                                              int* __restrict__ counts, int E) {
    int g = blockIdx.x * 256 + threadIdx.x;
    if (g < E) atomicAdd(&counts[row[g]], 1);
}

// ---------------- exclusive scan (single block) -----------------------------
__global__ __launch_bounds__(1024) void k_scan(const int* __restrict__ counts,
                                               int* __restrict__ row_start,
                                               int* __restrict__ cursor, int N) {
    __shared__ int sh[1024];
    int tid = threadIdx.x;
    int items = (N + 1023) >> 10;
    int base = tid * items;
    int tot = 0;
    for (int i = 0; i < items; ++i) { int idx = base + i; if (idx < N) tot += counts[idx]; }
    sh[tid] = tot;
    __syncthreads();
    for (int off = 1; off < 1024; off <<= 1) {
        int v = (tid >= off) ? sh[tid - off] : 0;
        __syncthreads();
        sh[tid] += v;
        __syncthreads();
    }
    int run = sh[tid] - tot;   // exclusive prefix
    for (int i = 0; i < items; ++i) {
        int idx = base + i;
        if (idx < N) { row_start[idx] = run; cursor[idx] = run; run += counts[idx]; }
    }
}

// ---------------- scatter: counting sort, sign packed into bit31 ------------
__global__ __launch_bounds__(256) void k_scatter(const int* __restrict__ row,
                                                 const int* __restrict__ col,
                                                 const void* __restrict__ vals,
                                                 int* __restrict__ cursor,
                                                 int* __restrict__ scol,
                                                 const int* __restrict__ flag, int E) {
    int g = blockIdx.x * 256 + threadIdx.x;
    if (g < E) {
        int r = row[g];
        int pos = atomicAdd(&cursor[r], 1);
        unsigned int sign;
        if (flag[0]) sign = ((const unsigned int*)vals)[g] >> 31;
        else         sign = (((const unsigned short*)vals)[g] >> 15) & 1u;
        scol[pos] = (int)((unsigned int)col[g] | (sign << 31));
    }
}

// ---------------- fused GEMM: h = X*W + b (bf16 out), a2 = |h|.a2_w + a2_b --
__global__ __launch_bounds__(256) void k_gemm(const void* __restrict__ feat,
                                              const unsigned short* __restrict__ Wsw,
                                              const void* __restrict__ bias,
                                              const void* __restrict__ a2w,
                                              const void* __restrict__ a2b,
                                              unsigned short* __restrict__ hout,
                                              float* __restrict__ a2,
                                              const int* __restrict__ flag, int N) {
    __shared__ unsigned short lws[DIN * DOUT];    // 64 KB swizzled W
    {
        uint4* dst = (uint4*)lws;
        const uint4* src = (const uint4*)Wsw;
        for (int i = threadIdx.x; i < DIN * DOUT / 8; i += 256) dst[i] = src[i];
    }
    __syncthreads();

    int is_f32 = flag[0];
    int wv = threadIdx.x >> 6, lane = threadIdx.x & 63;
    int quad = lane >> 4, c = lane & 15;
    int node_base = blockIdx.x * 64 + wv * 16;

    int arow_n = node_base + c;
    if (arow_n >= N) arow_n = N - 1;                       // clamp tail loads
    const uint4* arow_b = (const uint4*)((const unsigned short*)feat + (size_t)arow_n * DIN);
    const f32x4* arow_f = (const f32x4*)((const float*)feat + (size_t)arow_n * DIN);

    f32x4 acc[8];
#pragma unroll
    for (int t = 0; t < 8; ++t) acc[t] = (f32x4){0.f, 0.f, 0.f, 0.f};

#pragma unroll
    for (int s = 0; s < 8; ++s) {
        U16x8 au;                                          // A[m=c][k=s*32+quad*8+j]
        if (is_f32) {
            f32x4 f0 = arow_f[(s * 4 + quad) * 2];
            f32x4 f1 = arow_f[(s * 4 + quad) * 2 + 1];
#pragma unroll
            for (int i = 0; i < 4; ++i) { au.s[i] = f2bf(f0[i]); au.s[4 + i] = f2bf(f1[i]); }
        } else {
            au.u = arow_b[s * 4 + quad];
        }
        bf16x8 a = au.v;
#pragma unroll
        for (int t = 0; t < 8; ++t) {
            U16x8 bu; bu.u = ((const uint4*)lws)[(s * 8 + t) * 64 + lane];
            acc[t] = __builtin_amdgcn_mfma_f32_16x16x32_bf16(a, bu.v, acc[t], 0, 0, 0);
        }
    }

    float bv[8], w2[8];
#pragma unroll
    for (int t = 0; t < 8; ++t) {
        int i = t * 16 + c;
        bv[t] = is_f32 ? ((const float*)bias)[i] : bf2f(((const unsigned short*)bias)[i]);
        w2[t] = is_f32 ? ((const float*)a2w)[i]  : bf2f(((const unsigned short*)a2w)[i]);
    }
    float s2[4] = {0.f, 0.f, 0.f, 0.f};
#pragma unroll
    for (int t = 0; t < 8; ++t) {
#pragma unroll
        for (int r = 0; r < 4; ++r) {
            float v = acc[t][r] + bv[t];
            int node = node_base + quad * 4 + r;          // D row = quad*4+reg
            if (node < N) hout[(size_t)node * DOUT + t * 16 + c] = f2bf(v);
            s2[r] += fabsf(v) * w2[t];
        }
    }
    float a2bv = is_f32 ? ((const float*)a2b)[0] : bf2f(((const unsigned short*)a2b)[0]);
#pragma unroll
    for (int r = 0; r < 4; ++r) {
        float v = s2[r];
        v += __shfl_xor(v, 1); v += __shfl_xor(v, 2);
        v += __shfl_xor(v, 4); v += __shfl_xor(v, 8);     // reduce 16 lanes of quad
        if (c == 0) {
            int node = node_base + quad * 4 + r;
            if (node < N) a2[node] = v + a2bv;
        }
    }
}

// ---------------- per-row softmax + SpMM ------------------------------------
__global__ __launch_bounds__(256) void k_spmm(const int* __restrict__ row_start,
                                              const int* __restrict__ cursor,
                                              const int* __restrict__ scol,
                                              const float* __restrict__ a2,
                                              const unsigned short* __restrict__ h,
                                              void* __restrict__ out,
                                              const int* __restrict__ flag, int N) {
    int r = blockIdx.x * 4 + (threadIdx.x >> 6);
    if (r >= N) return;
    int lane = threadIdx.x & 63;
    int start = row_start[r];
    int end = cursor[r];          // after scatter, cursor == row end

    float m = -1e30f;
    for (int e = start + lane; e < end; e += 64) {
        int cc = scol[e] & 0x7fffffff;
        m = fmaxf(m, a2[cc]);
    }
#pragma unroll
    for (int off = 1; off < 64; off <<= 1) m = fmaxf(m, __shfl_xor(m, off));

    float dsum = 0.f, acc0 = 0.f, acc1 = 0.f;
    const unsigned int* h2 = (const unsigned int*)h;      // 2 bf16 per uint
    for (int base = start; base < end; base += 64) {
        int idx = base + lane;
        int sc = (idx < end) ? scol[idx] : 0;
        int cc = sc & 0x7fffffff;
        float ex = 0.f;
        if (idx < end) ex = __expf(a2[cc] - m);
        dsum += ex;
        float exs = (sc < 0) ? -ex : ex;                  // apply orientation sign
        int cnt = min(64, end - base);
        for (int j = 0; j < cnt; ++j) {
            float w = __shfl(exs, j);
            int colj = __shfl(cc, j);
            unsigned int u = h2[(size_t)colj * (DOUT / 2) + lane];
            union { unsigned int uu; float f; } lo, hi;
            lo.uu = u << 16;
            hi.uu = u & 0xffff0000u;
            acc0 += w * lo.f;
            acc1 += w * hi.f;
        }
    }
#pragma unroll
    for (int off = 1; off < 64; off <<= 1) dsum += __shfl_xor(dsum, off);
    float inv = (end > start) ? 1.0f / dsum : 0.f;
    float o0 = acc0 * inv, o1 = acc1 * inv;
    if (flag[0]) {
        float2 o; o.x = o0; o.y = o1;                     // cols 2*lane, 2*lane+1
        ((float2*)out)[(size_t)r * (DOUT / 2) + lane] = o;
    } else {
        unsigned int o = (unsigned int)f2bf(o0) | ((unsigned int)f2bf(o1) << 16);
        ((unsigned int*)out)[(size_t)r * (DOUT / 2) + lane] = o;
    }
}

// ---------------- launch ----------------------------------------------------
extern "C" void kernel_launch(void* const* d_in, const int* in_sizes, int n_in,
                              void* d_out, int out_size, void* d_ws, size_t ws_size,
                              hipStream_t stream) {
    const void* feat = d_in[0];
    const void* vals = d_in[1];
    const void* W    = d_in[2];
    const void* bias = d_in[3];
    // d_in[4] = a1_w, d_in[5] = a1_b — cancel in per-row softmax, unused
    const void* a2w  = d_in[6];
    const void* a2b  = d_in[7];
    const int* row = (const int*)d_in[8];
    const int* col = (const int*)d_in[9];

    int E = in_sizes[8];
    int N = in_sizes[0] / DIN;

    uint8_t* ws = (uint8_t*)d_ws;
    size_t off = 0;
    unsigned short* h = (unsigned short*)(ws + off); off += (size_t)N * DOUT * 2;
    float* a2        = (float*)(ws + off);           off += (size_t)N * 4;
    int* counts      = (int*)(ws + off);             off += (size_t)N * 4;
    int* row_start   = (int*)(ws + off);             off += (size_t)N * 4;
    int* cursor      = (int*)(ws + off);             off += (size_t)N * 4;
    int* scol        = (int*)(ws + off);             off += (size_t)E * 4;
    unsigned short* Wsw = (unsigned short*)(ws + off); off += (size_t)DIN * DOUT * 2;
    int* flag        = (int*)(ws + off);             off += 256;

    k_detect<<<1, 64, 0, stream>>>((const unsigned int*)vals, flag);
    int nb_prep = (N + 255) / 256; if (nb_prep < 16) nb_prep = 16;
    k_prep<<<nb_prep, 256, 0, stream>>>(W, Wsw, counts, flag, N);
    k_hist<<<(E + 255) / 256, 256, 0, stream>>>(row, counts, E);
    k_scan<<<1, 1024, 0, stream>>>(counts, row_start, cursor, N);
    k_scatter<<<(E + 255) / 256, 256, 0, stream>>>(row, col, vals, cursor, scol, flag, E);
    k_gemm<<<(N + 63) / 64, 256, 0, stream>>>(feat, Wsw, bias, a2w, a2b, h, a2, flag, N);
    k_spmm<<<(N + 3) / 4, 256, 0, stream>>>(row_start, cursor, scol, a2, h, d_out, flag, N);
}

// Round 3
// 521.167 us; speedup vs baseline: 1.4667x; 1.4667x over previous
//
#include <hip/hip_runtime.h>
#include <hip/hip_bf16.h>
#include <cstdint>
#include <cstddef>

#define DIN 256
#define DOUT 128

typedef __bf16 bf16x8 __attribute__((ext_vector_type(8)));
typedef float f32x4 __attribute__((ext_vector_type(4)));

union U16x8 { uint4 u; bf16x8 v; unsigned short s[8]; };

__device__ __forceinline__ float bf2f(unsigned short s) {
    union { unsigned int u; float f; } c; c.u = ((unsigned int)s) << 16; return c.f;
}
__device__ __forceinline__ unsigned short f2bf(float f) {
    union { float f; unsigned int u; } c; c.f = f;
    unsigned int u = c.u;
    unsigned int r = (u + 0x7fffu + ((u >> 16) & 1u)) >> 16;
    return (unsigned short)r;
}

// ---------------- dtype detect: values are exactly +-1.0 --------------------
__global__ void k_detect(const unsigned int* __restrict__ vals, int* __restrict__ flag) {
    if (threadIdx.x == 0 && blockIdx.x == 0)
        flag[0] = ((vals[0] & 0xFFFFu) == 0u) ? 1 : 0;
}

// ---------------- prep: zero counts + build swizzled W (B-fragment order) ---
__global__ __launch_bounds__(256) void k_prep(const void* __restrict__ W,
                                              unsigned short* __restrict__ Wsw,
                                              int* __restrict__ counts,
                                              const int* __restrict__ flag, int N) {
    int g = blockIdx.x * 256 + threadIdx.x;
    if (g < N) counts[g] = 0;
    if (g < 8 * 8 * 64) {
        int is_f32 = flag[0];
        int lane = g & 63;
        int st = g >> 6;            // s*8 + t
        int s = st >> 3, t = st & 7;
        int quad = lane >> 4, c = lane & 15;
        int kbase = s * 32 + quad * 8;
        int col = t * 16 + c;
        U16x8 u;
#pragma unroll
        for (int j = 0; j < 8; ++j) {
            size_t idx = (size_t)(kbase + j) * DOUT + col;
            u.s[j] = is_f32 ? f2bf(((const float*)W)[idx])
                            : ((const unsigned short*)W)[idx];
        }
        ((uint4*)Wsw)[g] = u.u;
    }
}

// ---------------- histogram -------------------------------------------------
__global__ __launch_bounds__(256) void k_hist(const int* __restrict__ row,
                                              int* __restrict__ counts, int E) {
    int g = blockIdx.x * 256 + threadIdx.x;
    if (g < E) atomicAdd(&counts[row[g]], 1);
}

// ---------------- hierarchical exclusive scan -------------------------------
// phase 1: per-block (1024 elems) local exclusive prefix + block totals
__global__ __launch_bounds__(256) void k_scan1(const int* __restrict__ counts,
                                               int* __restrict__ locpre,
                                               int* __restrict__ bsum, int N) {
    int base = blockIdx.x * 1024 + threadIdx.x * 4;
    int4 v = {0, 0, 0, 0};
    if (base + 3 < N) v = *(const int4*)(counts + base);
    else {
        int a[4] = {0, 0, 0, 0};
        for (int i = 0; i < 4; ++i) if (base + i < N) a[i] = counts[base + i];
        v.x = a[0]; v.y = a[1]; v.z = a[2]; v.w = a[3];
    }
    int tsum = v.x + v.y + v.z + v.w;
    int lane = threadIdx.x & 63;
    int incl = tsum;
#pragma unroll
    for (int off = 1; off < 64; off <<= 1) {
        int n = __shfl_up(incl, off);
        if (lane >= off) incl += n;
    }
    __shared__ int wsum[4];
    int wv = threadIdx.x >> 6;
    if (lane == 63) wsum[wv] = incl;
    __syncthreads();
    int wbase = 0;
    for (int i = 0; i < wv; ++i) wbase += wsum[i];
    int excl = wbase + incl - tsum;
    int4 o;
    o.x = excl; o.y = o.x + v.x; o.z = o.y + v.y; o.w = o.z + v.z;
    if (base + 3 < N) *(int4*)(locpre + base) = o;
    else {
        int oo[4] = {o.x, o.y, o.z, o.w};
        for (int i = 0; i < 4; ++i) if (base + i < N) locpre[base + i] = oo[i];
    }
    if (threadIdx.x == 255) bsum[blockIdx.x] = wbase + incl;   // block total
}

// phase 2: exclusive scan of block totals (B <= 256)
__global__ __launch_bounds__(256) void k_scan2(int* __restrict__ bsum, int B) {
    __shared__ int sh[256];
    int tid = threadIdx.x;
    int v = (tid < B) ? bsum[tid] : 0;
    sh[tid] = v;
    __syncthreads();
    for (int off = 1; off < 256; off <<= 1) {
        int n = (tid >= off) ? sh[tid - off] : 0;
        __syncthreads();
        sh[tid] += n;
        __syncthreads();
    }
    if (tid < B) bsum[tid] = sh[tid] - v;     // exclusive
}

// phase 3: add block offsets, emit row_start + cursor
__global__ __launch_bounds__(256) void k_scan3(const int* __restrict__ locpre,
                                               const int* __restrict__ bsum,
                                               int* __restrict__ row_start,
                                               int* __restrict__ cursor, int N) {
    int base = blockIdx.x * 1024 + threadIdx.x * 4;
    int add = bsum[blockIdx.x];
    if (base + 3 < N) {
        int4 v = *(const int4*)(locpre + base);
        v.x += add; v.y += add; v.z += add; v.w += add;
        *(int4*)(row_start + base) = v;
        *(int4*)(cursor + base) = v;
    } else {
        for (int i = 0; i < 4; ++i)
            if (base + i < N) {
                int t = locpre[base + i] + add;
                row_start[base + i] = t;
                cursor[base + i] = t;
            }
    }
}

// ---------------- scatter: counting sort, sign packed into bit31 ------------
__global__ __launch_bounds__(256) void k_scatter(const int* __restrict__ row,
                                                 const int* __restrict__ col,
                                                 const void* __restrict__ vals,
                                                 int* __restrict__ cursor,
                                                 int* __restrict__ scol,
                                                 const int* __restrict__ flag, int E) {
    int g = blockIdx.x * 256 + threadIdx.x;
    if (g < E) {
        int r = row[g];
        int pos = atomicAdd(&cursor[r], 1);
        unsigned int sign;
        if (flag[0]) sign = ((const unsigned int*)vals)[g] >> 31;
        else         sign = (((const unsigned short*)vals)[g] >> 15) & 1u;
        scol[pos] = (int)((unsigned int)col[g] | (sign << 31));
    }
}

// ---------------- fused GEMM: h = X*W + b (bf16 out), a2 = |h|.a2_w + a2_b --
__global__ __launch_bounds__(256) void k_gemm(const void* __restrict__ feat,
                                              const unsigned short* __restrict__ Wsw,
                                              const void* __restrict__ bias,
                                              const void* __restrict__ a2w,
                                              const void* __restrict__ a2b,
                                              unsigned short* __restrict__ hout,
                                              float* __restrict__ a2,
                                              const int* __restrict__ flag, int N) {
    __shared__ unsigned short lws[DIN * DOUT];    // 64 KB swizzled W
    {
        uint4* dst = (uint4*)lws;
        const uint4* src = (const uint4*)Wsw;
        for (int i = threadIdx.x; i < DIN * DOUT / 8; i += 256) dst[i] = src[i];
    }
    __syncthreads();

    int is_f32 = flag[0];
    int wv = threadIdx.x >> 6, lane = threadIdx.x & 63;
    int quad = lane >> 4, c = lane & 15;
    int node_base = blockIdx.x * 64 + wv * 16;

    int arow_n = node_base + c;
    if (arow_n >= N) arow_n = N - 1;                       // clamp tail loads
    const uint4* arow_b = (const uint4*)((const unsigned short*)feat + (size_t)arow_n * DIN);
    const f32x4* arow_f = (const f32x4*)((const float*)feat + (size_t)arow_n * DIN);

    f32x4 acc[8];
#pragma unroll
    for (int t = 0; t < 8; ++t) acc[t] = (f32x4){0.f, 0.f, 0.f, 0.f};

#pragma unroll
    for (int s = 0; s < 8; ++s) {
        U16x8 au;                                          // A[m=c][k=s*32+quad*8+j]
        if (is_f32) {
            f32x4 f0 = arow_f[(s * 4 + quad) * 2];
            f32x4 f1 = arow_f[(s * 4 + quad) * 2 + 1];
#pragma unroll
            for (int i = 0; i < 4; ++i) { au.s[i] = f2bf(f0[i]); au.s[4 + i] = f2bf(f1[i]); }
        } else {
            au.u = arow_b[s * 4 + quad];
        }
        bf16x8 a = au.v;
#pragma unroll
        for (int t = 0; t < 8; ++t) {
            U16x8 bu; bu.u = ((const uint4*)lws)[(s * 8 + t) * 64 + lane];
            acc[t] = __builtin_amdgcn_mfma_f32_16x16x32_bf16(a, bu.v, acc[t], 0, 0, 0);
        }
    }

    float bv[8], w2[8];
#pragma unroll
    for (int t = 0; t < 8; ++t) {
        int i = t * 16 + c;
        bv[t] = is_f32 ? ((const float*)bias)[i] : bf2f(((const unsigned short*)bias)[i]);
        w2[t] = is_f32 ? ((const float*)a2w)[i]  : bf2f(((const unsigned short*)a2w)[i]);
    }
    float s2[4] = {0.f, 0.f, 0.f, 0.f};
#pragma unroll
    for (int t = 0; t < 8; ++t) {
#pragma unroll
        for (int r = 0; r < 4; ++r) {
            float v = acc[t][r] + bv[t];
            int node = node_base + quad * 4 + r;          // D row = quad*4+reg
            if (node < N) hout[(size_t)node * DOUT + t * 16 + c] = f2bf(v);
            s2[r] += fabsf(v) * w2[t];
        }
    }
    float a2bv = is_f32 ? ((const float*)a2b)[0] : bf2f(((const unsigned short*)a2b)[0]);
#pragma unroll
    for (int r = 0; r < 4; ++r) {
        float v = s2[r];
        v += __shfl_xor(v, 1); v += __shfl_xor(v, 2);
        v += __shfl_xor(v, 4); v += __shfl_xor(v, 8);     // reduce 16 lanes of quad
        if (c == 0) {
            int node = node_base + quad * 4 + r;
            if (node < N) a2[node] = v + a2bv;
        }
    }
}

// ---------------- per-row softmax + SpMM ------------------------------------
__global__ __launch_bounds__(256) void k_spmm(const int* __restrict__ row_start,
                                              const int* __restrict__ cursor,
                                              const int* __restrict__ scol,
                                              const float* __restrict__ a2,
                                              const unsigned short* __restrict__ h,
                                              void* __restrict__ out,
                                              const int* __restrict__ flag, int N) {
    int r = blockIdx.x * 4 + (threadIdx.x >> 6);
    if (r >= N) return;
    int lane = threadIdx.x & 63;
    int start = row_start[r];
    int end = cursor[r];          // after scatter, cursor == row end

    float m = -1e30f;
    for (int e = start + lane; e < end; e += 64) {
        int cc = scol[e] & 0x7fffffff;
        m = fmaxf(m, a2[cc]);
    }
#pragma unroll
    for (int off = 1; off < 64; off <<= 1) m = fmaxf(m, __shfl_xor(m, off));

    float dsum = 0.f, acc0 = 0.f, acc1 = 0.f;
    const unsigned int* h2 = (const unsigned int*)h;      // 2 bf16 per uint
    for (int base = start; base < end; base += 64) {
        int idx = base + lane;
        int sc = (idx < end) ? scol[idx] : 0;
        int cc = sc & 0x7fffffff;
        float ex = 0.f;
        if (idx < end) ex = __expf(a2[cc] - m);
        dsum += ex;
        float exs = (sc < 0) ? -ex : ex;                  // apply orientation sign
        int cnt = min(64, end - base);
        for (int j = 0; j < cnt; ++j) {
            float w = __shfl(exs, j);
            int colj = __shfl(cc, j);
            unsigned int u = h2[(size_t)colj * (DOUT / 2) + lane];
            union { unsigned int uu; float f; } lo, hi;
            lo.uu = u << 16;
            hi.uu = u & 0xffff0000u;
            acc0 += w * lo.f;
            acc1 += w * hi.f;
        }
    }
#pragma unroll
    for (int off = 1; off < 64; off <<= 1) dsum += __shfl_xor(dsum, off);
    float inv = (end > start) ? 1.0f / dsum : 0.f;
    float o0 = acc0 * inv, o1 = acc1 * inv;
    if (flag[0]) {
        float2 o; o.x = o0; o.y = o1;                     // cols 2*lane, 2*lane+1
        ((float2*)out)[(size_t)r * (DOUT / 2) + lane] = o;
    } else {
        unsigned int o = (unsigned int)f2bf(o0) | ((unsigned int)f2bf(o1) << 16);
        ((unsigned int*)out)[(size_t)r * (DOUT / 2) + lane] = o;
    }
}

// ---------------- launch ----------------------------------------------------
extern "C" void kernel_launch(void* const* d_in, const int* in_sizes, int n_in,
                              void* d_out, int out_size, void* d_ws, size_t ws_size,
                              hipStream_t stream) {
    const void* feat = d_in[0];
    const void* vals = d_in[1];
    const void* W    = d_in[2];
    const void* bias = d_in[3];
    // d_in[4] = a1_w, d_in[5] = a1_b — cancel in per-row softmax, unused
    const void* a2w  = d_in[6];
    const void* a2b  = d_in[7];
    const int* row = (const int*)d_in[8];
    const int* col = (const int*)d_in[9];

    int E = in_sizes[8];
    int N = in_sizes[0] / DIN;

    uint8_t* ws = (uint8_t*)d_ws;
    size_t off = 0;
    auto alloc = [&](size_t bytes) -> void* {
        void* p = ws + off;
        off += (bytes + 15) & ~(size_t)15;
        return p;
    };
    unsigned short* h   = (unsigned short*)alloc((size_t)N * DOUT * 2);
    float* a2           = (float*)alloc((size_t)N * 4);
    int* counts         = (int*)alloc((size_t)N * 4);
    int* row_start      = (int*)alloc((size_t)N * 4);
    int* cursor         = (int*)alloc((size_t)N * 4);
    int* scol           = (int*)alloc((size_t)E * 4);
    unsigned short* Wsw = (unsigned short*)alloc((size_t)DIN * DOUT * 2);
    int* flag           = (int*)alloc(256);
    int* locpre         = (int*)alloc((size_t)N * 4);
    int* bsum           = (int*)alloc(1024);

    int B = (N + 1023) / 1024;    // scan blocks (<= 256 for N <= 262144)

    k_detect<<<1, 64, 0, stream>>>((const unsigned int*)vals, flag);
    int nb_prep = (N + 255) / 256; if (nb_prep < 16) nb_prep = 16;
    k_prep<<<nb_prep, 256, 0, stream>>>(W, Wsw, counts, flag, N);
    k_hist<<<(E + 255) / 256, 256, 0, stream>>>(row, counts, E);
    k_scan1<<<B, 256, 0, stream>>>(counts, locpre, bsum, N);
    k_scan2<<<1, 256, 0, stream>>>(bsum, B);
    k_scan3<<<B, 256, 0, stream>>>(locpre, bsum, row_start, cursor, N);
    k_scatter<<<(E + 255) / 256, 256, 0, stream>>>(row, col, vals, cursor, scol, flag, E);
    k_gemm<<<(N + 63) / 64, 256, 0, stream>>>(feat, Wsw, bias, a2w, a2b, h, a2, flag, N);
    k_spmm<<<(N + 3) / 4, 256, 0, stream>>>(row_start, cursor, scol, a2, h, d_out, flag, N);
}

// Round 4
// 486.108 us; speedup vs baseline: 1.5725x; 1.0721x over previous
//
#include <hip/hip_runtime.h>
#include <hip/hip_bf16.h>
#include <cstdint>
#include <cstddef>

#define DIN 256
#define DOUT 128

typedef __bf16 bf16x8 __attribute__((ext_vector_type(8)));
typedef float f32x4 __attribute__((ext_vector_type(4)));

union U16x8 { uint4 u; bf16x8 v; unsigned short s[8]; };

__device__ __forceinline__ float bf2f(unsigned short s) {
    union { unsigned int u; float f; } c; c.u = ((unsigned int)s) << 16; return c.f;
}
__device__ __forceinline__ unsigned short f2bf(float f) {
    union { float f; unsigned int u; } c; c.f = f;
    unsigned int u = c.u;
    unsigned int r = (u + 0x7fffu + ((u >> 16) & 1u)) >> 16;
    return (unsigned short)r;
}

// ---------------- dtype detect: values are exactly +-1.0 --------------------
__global__ void k_detect(const unsigned int* __restrict__ vals, int* __restrict__ flag) {
    if (threadIdx.x == 0 && blockIdx.x == 0)
        flag[0] = ((vals[0] & 0xFFFFu) == 0u) ? 1 : 0;
}

// ---------------- prep: zero counts + build swizzled W (B-fragment order) ---
__global__ __launch_bounds__(256) void k_prep(const void* __restrict__ W,
                                              unsigned short* __restrict__ Wsw,
                                              int* __restrict__ counts,
                                              const int* __restrict__ flag, int N) {
    int g = blockIdx.x * 256 + threadIdx.x;
    if (g < N) counts[g] = 0;
    if (g < 8 * 8 * 64) {
        int is_f32 = flag[0];
        int lane = g & 63;
        int st = g >> 6;            // s*8 + t
        int s = st >> 3, t = st & 7;
        int quad = lane >> 4, c = lane & 15;
        int kbase = s * 32 + quad * 8;
        int col = t * 16 + c;
        U16x8 u;
#pragma unroll
        for (int j = 0; j < 8; ++j) {
            size_t idx = (size_t)(kbase + j) * DOUT + col;
            u.s[j] = is_f32 ? f2bf(((const float*)W)[idx])
                            : ((const unsigned short*)W)[idx];
        }
        ((uint4*)Wsw)[g] = u.u;
    }
}

// ---------------- histogram (4 edges / thread) ------------------------------
__global__ __launch_bounds__(256) void k_hist(const int* __restrict__ row,
                                              int* __restrict__ counts, int E) {
    int base = (blockIdx.x * 256 + threadIdx.x) * 4;
    if (base + 3 < E) {
        int4 v = *(const int4*)(row + base);
        atomicAdd(&counts[v.x], 1);
        atomicAdd(&counts[v.y], 1);
        atomicAdd(&counts[v.z], 1);
        atomicAdd(&counts[v.w], 1);
    } else {
        for (int i = 0; i < 4; ++i)
            if (base + i < E) atomicAdd(&counts[row[base + i]], 1);
    }
}

// ---------------- hierarchical exclusive scan -------------------------------
__global__ __launch_bounds__(256) void k_scan1(const int* __restrict__ counts,
                                               int* __restrict__ locpre,
                                               int* __restrict__ bsum, int N) {
    int base = blockIdx.x * 1024 + threadIdx.x * 4;
    int4 v = {0, 0, 0, 0};
    if (base + 3 < N) v = *(const int4*)(counts + base);
    else {
        int a[4] = {0, 0, 0, 0};
        for (int i = 0; i < 4; ++i) if (base + i < N) a[i] = counts[base + i];
        v.x = a[0]; v.y = a[1]; v.z = a[2]; v.w = a[3];
    }
    int tsum = v.x + v.y + v.z + v.w;
    int lane = threadIdx.x & 63;
    int incl = tsum;
#pragma unroll
    for (int off = 1; off < 64; off <<= 1) {
        int n = __shfl_up(incl, off);
        if (lane >= off) incl += n;
    }
    __shared__ int wsum[4];
    int wv = threadIdx.x >> 6;
    if (lane == 63) wsum[wv] = incl;
    __syncthreads();
    int wbase = 0;
    for (int i = 0; i < wv; ++i) wbase += wsum[i];
    int excl = wbase + incl - tsum;
    int4 o;
    o.x = excl; o.y = o.x + v.x; o.z = o.y + v.y; o.w = o.z + v.z;
    if (base + 3 < N) *(int4*)(locpre + base) = o;
    else {
        int oo[4] = {o.x, o.y, o.z, o.w};
        for (int i = 0; i < 4; ++i) if (base + i < N) locpre[base + i] = oo[i];
    }
    if (threadIdx.x == 255) bsum[blockIdx.x] = wbase + incl;   // block total
}

__global__ __launch_bounds__(256) void k_scan2(int* __restrict__ bsum, int B) {
    __shared__ int sh[256];
    int tid = threadIdx.x;
    int v = (tid < B) ? bsum[tid] : 0;
    sh[tid] = v;
    __syncthreads();
    for (int off = 1; off < 256; off <<= 1) {
        int n = (tid >= off) ? sh[tid - off] : 0;
        __syncthreads();
        sh[tid] += n;
        __syncthreads();
    }
    if (tid < B) bsum[tid] = sh[tid] - v;     // exclusive
}

__global__ __launch_bounds__(256) void k_scan3(const int* __restrict__ locpre,
                                               const int* __restrict__ bsum,
                                               int* __restrict__ row_start,
                                               int* __restrict__ cursor, int N) {
    int base = blockIdx.x * 1024 + threadIdx.x * 4;
    int add = bsum[blockIdx.x];
    if (base + 3 < N) {
        int4 v = *(const int4*)(locpre + base);
        v.x += add; v.y += add; v.z += add; v.w += add;
        *(int4*)(row_start + base) = v;
        *(int4*)(cursor + base) = v;
    } else {
        for (int i = 0; i < 4; ++i)
            if (base + i < N) {
                int t = locpre[base + i] + add;
                row_start[base + i] = t;
                cursor[base + i] = t;
            }
    }
}

// ---------------- scatter: counting sort, sign packed into bit31 ------------
__global__ __launch_bounds__(256) void k_scatter(const int* __restrict__ row,
                                                 const int* __restrict__ col,
                                                 const void* __restrict__ vals,
                                                 int* __restrict__ cursor,
                                                 int* __restrict__ scol,
                                                 const int* __restrict__ flag, int E) {
    int base = (blockIdx.x * 256 + threadIdx.x) * 4;
    int is_f32 = flag[0];
    if (base + 3 < E) {
        int4 rr = *(const int4*)(row + base);
        int4 cc = *(const int4*)(col + base);
        unsigned int sg[4];
        if (is_f32) {
            uint4 vv = *(const uint4*)((const unsigned int*)vals + base);
            sg[0] = vv.x >> 31; sg[1] = vv.y >> 31; sg[2] = vv.z >> 31; sg[3] = vv.w >> 31;
        } else {
            uint2 vv = *(const uint2*)((const unsigned short*)vals + base);
            sg[0] = (vv.x >> 15) & 1u; sg[1] = vv.x >> 31;
            sg[2] = (vv.y >> 15) & 1u; sg[3] = vv.y >> 31;
        }
        int r4[4] = {rr.x, rr.y, rr.z, rr.w};
        int c4[4] = {cc.x, cc.y, cc.z, cc.w};
#pragma unroll
        for (int i = 0; i < 4; ++i) {
            int pos = atomicAdd(&cursor[r4[i]], 1);
            scol[pos] = (int)((unsigned int)c4[i] | (sg[i] << 31));
        }
    } else {
        for (int i = 0; i < 4; ++i) {
            int g = base + i;
            if (g < E) {
                int r = row[g];
                int pos = atomicAdd(&cursor[r], 1);
                unsigned int sign;
                if (is_f32) sign = ((const unsigned int*)vals)[g] >> 31;
                else        sign = (((const unsigned short*)vals)[g] >> 15) & 1u;
                scol[pos] = (int)((unsigned int)col[g] | (sign << 31));
            }
        }
    }
}

// ---- fused GEMM: h = X*W + b (bf16 out), ea2 = exp(|h|.a2_w + a2_b) --------
__global__ __launch_bounds__(256) void k_gemm(const void* __restrict__ feat,
                                              const unsigned short* __restrict__ Wsw,
                                              const void* __restrict__ bias,
                                              const void* __restrict__ a2w,
                                              const void* __restrict__ a2b,
                                              unsigned short* __restrict__ hout,
                                              float* __restrict__ ea2,
                                              const int* __restrict__ flag, int N) {
    __shared__ unsigned short lws[DIN * DOUT];    // 64 KB swizzled W
    {
        uint4* dst = (uint4*)lws;
        const uint4* src = (const uint4*)Wsw;
        for (int i = threadIdx.x; i < DIN * DOUT / 8; i += 256) dst[i] = src[i];
    }
    __syncthreads();

    int is_f32 = flag[0];
    int wv = threadIdx.x >> 6, lane = threadIdx.x & 63;
    int quad = lane >> 4, c = lane & 15;
    int node_base = blockIdx.x * 64 + wv * 16;

    int arow_n = node_base + c;
    if (arow_n >= N) arow_n = N - 1;                       // clamp tail loads
    const uint4* arow_b = (const uint4*)((const unsigned short*)feat + (size_t)arow_n * DIN);
    const f32x4* arow_f = (const f32x4*)((const float*)feat + (size_t)arow_n * DIN);

    f32x4 acc[8];
#pragma unroll
    for (int t = 0; t < 8; ++t) acc[t] = (f32x4){0.f, 0.f, 0.f, 0.f};

#pragma unroll
    for (int s = 0; s < 8; ++s) {
        U16x8 au;                                          // A[m=c][k=s*32+quad*8+j]
        if (is_f32) {
            f32x4 f0 = arow_f[(s * 4 + quad) * 2];
            f32x4 f1 = arow_f[(s * 4 + quad) * 2 + 1];
#pragma unroll
            for (int i = 0; i < 4; ++i) { au.s[i] = f2bf(f0[i]); au.s[4 + i] = f2bf(f1[i]); }
        } else {
            au.u = arow_b[s * 4 + quad];
        }
        bf16x8 a = au.v;
#pragma unroll
        for (int t = 0; t < 8; ++t) {
            U16x8 bu; bu.u = ((const uint4*)lws)[(s * 8 + t) * 64 + lane];
            acc[t] = __builtin_amdgcn_mfma_f32_16x16x32_bf16(a, bu.v, acc[t], 0, 0, 0);
        }
    }

    float bv[8], w2[8];
#pragma unroll
    for (int t = 0; t < 8; ++t) {
        int i = t * 16 + c;
        bv[t] = is_f32 ? ((const float*)bias)[i] : bf2f(((const unsigned short*)bias)[i]);
        w2[t] = is_f32 ? ((const float*)a2w)[i]  : bf2f(((const unsigned short*)a2w)[i]);
    }
    float s2[4] = {0.f, 0.f, 0.f, 0.f};
#pragma unroll
    for (int t = 0; t < 8; ++t) {
#pragma unroll
        for (int r = 0; r < 4; ++r) {
            float v = acc[t][r] + bv[t];
            int node = node_base + quad * 4 + r;          // D row = quad*4+reg
            if (node < N) hout[(size_t)node * DOUT + t * 16 + c] = f2bf(v);
            s2[r] += fabsf(v) * w2[t];
        }
    }
    float a2bv = is_f32 ? ((const float*)a2b)[0] : bf2f(((const unsigned short*)a2b)[0]);
#pragma unroll
    for (int r = 0; r < 4; ++r) {
        float v = s2[r];
        v += __shfl_xor(v, 1); v += __shfl_xor(v, 2);
        v += __shfl_xor(v, 4); v += __shfl_xor(v, 8);     // reduce 16 lanes of quad
        if (c == 0) {
            int node = node_base + quad * 4 + r;
            if (node < N) ea2[node] = __expf(v + a2bv);   // softmax shift-free
        }
    }
}

// ---------------- per-row softmax + SpMM (4-edge groups) --------------------
__global__ __launch_bounds__(256) void k_spmm(const int* __restrict__ row_start,
                                              const int* __restrict__ cursor,
                                              const int* __restrict__ scol,
                                              const float* __restrict__ ea2,
                                              const unsigned short* __restrict__ h,
                                              void* __restrict__ out,
                                              const int* __restrict__ flag, int N) {
    int r = blockIdx.x * 4 + (threadIdx.x >> 6);
    if (r >= N) return;
    int lane = threadIdx.x & 63;
    int g = lane >> 4, c = lane & 15;
    int start = row_start[r];
    int end = cursor[r];          // after scatter, cursor == row end

    float dsum = 0.f;
    float acc[8];
#pragma unroll
    for (int k = 0; k < 8; ++k) acc[k] = 0.f;

    const uint4* h4 = (const uint4*)h;                // 16 uint4 per 128-col row

    for (int base = start; base < end; base += 64) {
        int idx = base + lane;
        int cnt = end - base; if (cnt > 64) cnt = 64;
        int sc = (idx < end) ? scol[idx] : 0;
        int cc = sc & 0x7fffffff;
        float w = (idx < end) ? ea2[cc] : 0.f;
        dsum += w;                                    // positive weight for denom
        if (sc < 0) w = -w;                           // orientation sign
        int iters = (cnt + 3) >> 2;
#pragma unroll 2
        for (int i = 0; i < iters; ++i) {
            int src = (i << 2) | g;                   // group g takes edge 4i+g
            float wj = __shfl(w, src);                // 0 for padded lanes
            int colj = __shfl(cc, src);
            uint4 u = h4[(size_t)colj * 16 + c];      // 16B of h row per lane
            union { unsigned int uu; float f; } lo, hi;
            lo.uu = u.x << 16; hi.uu = u.x & 0xffff0000u;
            acc[0] += wj * lo.f; acc[1] += wj * hi.f;
            lo.uu = u.y << 16; hi.uu = u.y & 0xffff0000u;
            acc[2] += wj * lo.f; acc[3] += wj * hi.f;
            lo.uu = u.z << 16; hi.uu = u.z & 0xffff0000u;
            acc[4] += wj * lo.f; acc[5] += wj * hi.f;
            lo.uu = u.w << 16; hi.uu = u.w & 0xffff0000u;
            acc[6] += wj * lo.f; acc[7] += wj * hi.f;
        }
    }

    // combine the 4 edge-groups, reduce denom
#pragma unroll
    for (int k = 0; k < 8; ++k) {
        acc[k] += __shfl_xor(acc[k], 16);
        acc[k] += __shfl_xor(acc[k], 32);
    }
#pragma unroll
    for (int off = 1; off < 64; off <<= 1) dsum += __shfl_xor(dsum, off);
    float inv = (dsum > 0.f) ? 1.0f / dsum : 0.f;

    if (lane < 16) {                                  // lane c owns cols c*8..c*8+7
        if (flag[0]) {
            float4 o0, o1;
            o0.x = acc[0] * inv; o0.y = acc[1] * inv; o0.z = acc[2] * inv; o0.w = acc[3] * inv;
            o1.x = acc[4] * inv; o1.y = acc[5] * inv; o1.z = acc[6] * inv; o1.w = acc[7] * inv;
            ((float4*)out)[(size_t)r * 32 + c * 2] = o0;
            ((float4*)out)[(size_t)r * 32 + c * 2 + 1] = o1;
        } else {
            uint4 o;
            o.x = (unsigned int)f2bf(acc[0] * inv) | ((unsigned int)f2bf(acc[1] * inv) << 16);
            o.y = (unsigned int)f2bf(acc[2] * inv) | ((unsigned int)f2bf(acc[3] * inv) << 16);
            o.z = (unsigned int)f2bf(acc[4] * inv) | ((unsigned int)f2bf(acc[5] * inv) << 16);
            o.w = (unsigned int)f2bf(acc[6] * inv) | ((unsigned int)f2bf(acc[7] * inv) << 16);
            ((uint4*)out)[(size_t)r * 16 + c] = o;
        }
    }
}

// ---------------- launch ----------------------------------------------------
extern "C" void kernel_launch(void* const* d_in, const int* in_sizes, int n_in,
                              void* d_out, int out_size, void* d_ws, size_t ws_size,
                              hipStream_t stream) {
    const void* feat = d_in[0];
    const void* vals = d_in[1];
    const void* W    = d_in[2];
    const void* bias = d_in[3];
    // d_in[4] = a1_w, d_in[5] = a1_b — cancel in per-row softmax, unused
    const void* a2w  = d_in[6];
    const void* a2b  = d_in[7];
    const int* row = (const int*)d_in[8];
    const int* col = (const int*)d_in[9];

    int E = in_sizes[8];
    int N = in_sizes[0] / DIN;

    uint8_t* ws = (uint8_t*)d_ws;
    size_t off = 0;
    auto alloc = [&](size_t bytes) -> void* {
        void* p = ws + off;
        off += (bytes + 15) & ~(size_t)15;
        return p;
    };
    unsigned short* h   = (unsigned short*)alloc((size_t)N * DOUT * 2);
    float* ea2          = (float*)alloc((size_t)N * 4);
    int* counts         = (int*)alloc((size_t)N * 4);
    int* row_start      = (int*)alloc((size_t)N * 4);
    int* cursor         = (int*)alloc((size_t)N * 4);
    int* scol           = (int*)alloc((size_t)E * 4);
    unsigned short* Wsw = (unsigned short*)alloc((size_t)DIN * DOUT * 2);
    int* flag           = (int*)alloc(256);
    int* locpre         = (int*)alloc((size_t)N * 4);
    int* bsum           = (int*)alloc(1024);

    int B = (N + 1023) / 1024;    // scan blocks (<= 256 for N <= 262144)

    k_detect<<<1, 64, 0, stream>>>((const unsigned int*)vals, flag);
    int nb_prep = (N + 255) / 256; if (nb_prep < 16) nb_prep = 16;
    k_prep<<<nb_prep, 256, 0, stream>>>(W, Wsw, counts, flag, N);
    k_hist<<<(E / 4 + 255) / 256, 256, 0, stream>>>(row, counts, E);
    k_scan1<<<B, 256, 0, stream>>>(counts, locpre, bsum, N);
    k_scan2<<<1, 256, 0, stream>>>(bsum, B);
    k_scan3<<<B, 256, 0, stream>>>(locpre, bsum, row_start, cursor, N);
    k_scatter<<<(E / 4 + 255) / 256, 256, 0, stream>>>(row, col, vals, cursor, scol, flag, E);
    k_gemm<<<(N + 63) / 64, 256, 0, stream>>>(feat, Wsw, bias, a2w, a2b, h, ea2, flag, N);
    k_spmm<<<(N + 3) / 4, 256, 0, stream>>>(row_start, cursor, scol, ea2, h, d_out, flag, N);
}